// Round 5
// baseline (721.554 us; speedup 1.0000x reference)
//
#include <hip/hip_runtime.h>

// MultiHeadSelfAttention: B=4, C=256, S=4096, heads=8, d=32.
// 5-kernel pipeline, all GEMMs on mfma_f32_16x16x32_bf16, fp32 accumulate.
//   k_prep_w: w_qkv/w_proj fp32 -> bf16 (row-major (out,in) kept)
//   k_prep_x: x (b,c,s) fp32 -> xT (b,s,c) bf16 via swizzled LDS transpose
//             (xT aliases the O buffer: dead once k_qkv finishes)
//   k_qkv : A=w bf16 rows, B=xT rows, both direct b128 loads ->
//           Qr (b,h,S,d) scaled by scale*log2e, Kq (b,h,S,d), Vt (b,h,d,S)
//   k_attn: flash attention, fixed-max softmax, key-split 2x per block.
//           __launch_bounds__(256,6): VGPR headroom so compiler avoids
//           accvgpr moves; explicit next-chunk K prefetch (double-buffered
//           frags) hides L2 latency under exp2/PV.
//   k_proj: A=O bf16 rows, B=wp bf16 rows -> direct coalesced f4 stores (B,C,S)

typedef __attribute__((ext_vector_type(8))) short short8;  // 8 x bf16 MFMA frag
typedef __attribute__((ext_vector_type(4))) float f4;

__device__ __forceinline__ short f2bs(float f) {  // fp32 -> bf16 (RNE)
  union { float f; unsigned u; } v; v.f = f;
  unsigned r = v.u + 0x7FFFu + ((v.u >> 16) & 1u);
  return (short)(r >> 16);
}

__device__ __forceinline__ int pkrne(float a, float b) {  // 2xf32 -> dword RNE
  return (int)((unsigned short)f2bs(a) | ((unsigned)f2bs(b) << 16));
}

// pack hi16(lo+0x8000), hi16(hi+0x8000) -> dword (round-half-up): 3 VALU
__device__ __forceinline__ int pkhu(float lo, float hi) {
  union { float f; unsigned u; } a, b; a.f = lo; b.f = hi;
  return (int)__builtin_amdgcn_perm(b.u + 0x8000u, a.u + 0x8000u, 0x07060302u);
}

// ---------------------------------------------------------------- prep: weights
__global__ __launch_bounds__(256) void k_prep_w(
    const float* __restrict__ wq, const float* __restrict__ wp,
    short* __restrict__ wqb, short* __restrict__ wpb) {
  const int i = blockIdx.x * 256 + threadIdx.x;  // f4 index; grid covers exactly
  const int NQ = 768 * 256 / 4;
  f4 v; short* dst; int off;
  if (i < NQ) { v = ((const f4*)wq)[i]; dst = wqb; off = i * 4; }
  else        { v = ((const f4*)wp)[i - NQ]; dst = wpb; off = (i - NQ) * 4; }
  int2 pr; pr.x = pkrne(v[0], v[1]); pr.y = pkrne(v[2], v[3]);
  *(int2*)(dst + off) = pr;
}

// ---------------------------------------------------------------- prep: x -> xT
// 64c x 64s tile per block. LDS tile[s][c'] with c-granule xor swizzle by s.
__global__ __launch_bounds__(256) void k_prep_x(
    const float* __restrict__ x, short* __restrict__ xT) {
  const int t = threadIdx.x;
  const int b = blockIdx.z, c0 = blockIdx.y * 64, s0 = blockIdx.x * 64;
  __shared__ __align__(16) short tile[64 * 64];
#pragma unroll
  for (int pass = 0; pass < 4; ++pass) {
    const int cl = pass * 16 + (t >> 4);
    const int sl = (t & 15) * 4;
    f4 v = *(const f4*)(x + ((size_t)(b * 256 + c0 + cl)) * 4096 + s0 + sl);
#pragma unroll
    for (int k = 0; k < 4; ++k) {
      const int s = sl + k;
      tile[s * 64 + (cl ^ ((s & 7) << 3))] = f2bs(v[k]);
    }
  }
  __syncthreads();
#pragma unroll
  for (int i = 0; i < 2; ++i) {
    const int s = t >> 2;
    const int gc = (t & 3) + i * 4;
    const int gg = gc ^ (s & 7);
    short8 row = *(const short8*)(tile + s * 64 + gg * 8);
    *(short8*)(xT + ((size_t)(b * 4096 + s0 + s)) * 256 + c0 + gc * 8) = row;
  }
}

// ---------------------------------------------------------------- kernel: qkv
// D[j][s] = sum_c w[j][c] * xT[s][c] (+bias).  A=w (m=j), B=xT (n=s).
// grid (256 s-tiles, 12 j-tiles), block 256 = 4 waves, wave = 16j x 64s.
__global__ __launch_bounds__(256) void k_qkv(
    const short* __restrict__ xT, const short* __restrict__ wqb,
    const float* __restrict__ bias,
    short* __restrict__ Qr, short* __restrict__ Kq, short* __restrict__ Vt) {
  const int tid = threadIdx.x;
  const int L = tid & 63, wv = tid >> 6;
  const int ln15 = L & 15, quad = L >> 4;
  const int mt = blockIdx.x;
  const int b = mt >> 6;
  const int s0 = (mt & 63) << 6;
  const int j0 = blockIdx.y << 6;
  const int jw = j0 + wv * 16;

  __shared__ __align__(16) short tl[4][1024];  // per-wave V transpose buffer

  f4 acc[4] = {{0,0,0,0},{0,0,0,0},{0,0,0,0},{0,0,0,0}};
  const short* wb = wqb + (jw + ln15) * 256 + quad * 8;
  const short* xb = xT + (size_t)(b * 4096 + s0 + ln15) * 256 + quad * 8;

#pragma unroll
  for (int cb = 0; cb < 256; cb += 32) {
    short8 af = *(const short8*)(wb + cb);
#pragma unroll
    for (int sub = 0; sub < 4; ++sub) {
      short8 bfr = *(const short8*)(xb + sub * (16 * 256) + cb);
      acc[sub] = __builtin_amdgcn_mfma_f32_16x16x32_bf16(af, bfr, acc[sub], 0, 0, 0);
    }
  }
  // C: col(ln15) = s-local, row(quad*4+r) = j-local
  float bj[4];
#pragma unroll
  for (int r = 0; r < 4; ++r) bj[r] = bias[jw + quad * 4 + r];

  const int type = j0 >> 8;  // 0=Q 1=K 2=V
  const int hj = jw & 255;
  const int bh = b * 8 + (hj >> 5);
  const int db = hj & 31;  // 0 or 16

  if (type != 2) {
    // Q/K -> row-major (s, d): pack 4 consecutive d -> b64 store per sub
    const float qsc = 0.17677669529663689f * 1.44269504088896f;
    const float mul = (type == 0) ? qsc : 1.0f;
    short* dst = (type == 0) ? Qr : Kq;
#pragma unroll
    for (int sub = 0; sub < 4; ++sub) {
      float v0 = (acc[sub][0] + bj[0]) * mul;
      float v1 = (acc[sub][1] + bj[1]) * mul;
      float v2 = (acc[sub][2] + bj[2]) * mul;
      float v3 = (acc[sub][3] + bj[3]) * mul;
      int2 pr; pr.x = pkhu(v0, v1); pr.y = pkhu(v2, v3);
      *(int2*)(dst + (size_t)(bh * 4096 + s0 + sub * 16 + ln15) * 32 + db + quad * 4) = pr;
    }
  } else {
    // V -> Vt (d, s) via per-wave swizzled LDS transpose
    short* tv = tl[wv];
#pragma unroll
    for (int sub = 0; sub < 4; ++sub) {
      const int s = sub * 16 + ln15;
#pragma unroll
      for (int r = 0; r < 4; ++r) {
        const int dl = quad * 4 + r;
        tv[dl * 64 + ((((s >> 3) ^ dl) & 7) << 3) + (s & 7)] = f2bs(acc[sub][r] + bj[r]);
      }
    }
#pragma unroll
    for (int i = 0; i < 2; ++i) {
      const int dl = i * 8 + (L >> 3);
      const int gs = L & 7;
      const int gg = gs ^ (dl & 7);
      short8 row = *(const short8*)(tv + dl * 64 + gg * 8);
      *(short8*)(Vt + (size_t)(bh * 32 + db + dl) * 4096 + s0 + gs * 8) = row;
    }
  }
}

// ---------------------------------------------------------------- kernel: attn
// Block = 4 waves: wave wv -> q-tile (wv&1), key-half (wv>>1).
// Per 64-key chunk: QK (A=K m=key, B=Q n=q) -> exp2 -> round-half-up pack ->
// ds_write_b64 ; PV (A=P b128 LDS reads, B=Vt direct b128). Next-chunk K
// frags prefetched into the alternate register buffer (no copies).
__global__ __launch_bounds__(256, 6) void k_attn(
    const short* __restrict__ Qr, const short* __restrict__ Kq,
    const short* __restrict__ Vt, short* __restrict__ O) {
  const int tid = threadIdx.x;
  const int L = tid & 63, wv = tid >> 6;
  const int ln15 = L & 15, quad = L >> 4;
  const int bh = blockIdx.y;
  const int b = bh >> 3, h = bh & 7;
  const int qt = wv & 1, half = wv >> 1;
  const int qb = blockIdx.x * 64 + qt * 32;

  const short* Qb = Qr + (size_t)bh * 4096 * 32;
  const short* Kb = Kq + (size_t)bh * 4096 * 32 + half * 2048 * 32;
  const short* Vb = Vt + (size_t)bh * 32 * 4096 + half * 2048;

  __shared__ __align__(16) short plds[4][2048];  // per-wave P (2 qs x 16q x 64k)
  __shared__ float l_up[2][32];
  short* pw = plds[wv];
  const int sw = ln15 & 14;  // granule xor-swizzle (even -> keeps b128 pairs)

  short8 qf[2];
#pragma unroll
  for (int qs = 0; qs < 2; ++qs)
    qf[qs] = *(const short8*)(Qb + (qb + qs * 16 + ln15) * 32 + quad * 8);

  f4 acc[2][2] = {{{0,0,0,0},{0,0,0,0}},{{0,0,0,0},{0,0,0,0}}};
  float lsum[2] = {0.f, 0.f};
  const f4 z4 = {0.f, 0.f, 0.f, 0.f};

  const short* kp = Kb + ln15 * 32 + quad * 8;
  const short* vp = Vb + ln15 * 4096 + quad * 8;

  short8 kfA[4], kfB[4];
#pragma unroll
  for (int t = 0; t < 4; ++t) kfA[t] = *(const short8*)(kp + t * 16 * 32);

  auto chunk = [&](int kb, short8* kfu, short8* kfn, int knext) {
    // prefetch next chunk's K frags first (vmcnt overlaps exp2+PV below)
#pragma unroll
    for (int t = 0; t < 4; ++t)
      kfn[t] = *(const short8*)(kp + (knext + t * 16) * 32);
    // ---- S = K Q^T, exp2, pack, one b64 write per (t,qs)
#pragma unroll
    for (int t = 0; t < 4; ++t) {
#pragma unroll
      for (int qs = 0; qs < 2; ++qs) {
        f4 sc = __builtin_amdgcn_mfma_f32_16x16x32_bf16(kfu[t], qf[qs], z4, 0, 0, 0);
        float p0 = __builtin_amdgcn_exp2f(sc[0]);
        float p1 = __builtin_amdgcn_exp2f(sc[1]);
        float p2 = __builtin_amdgcn_exp2f(sc[2]);
        float p3 = __builtin_amdgcn_exp2f(sc[3]);
        lsum[qs] += (p0 + p1) + (p2 + p3);
        int2 pr;
        pr.x = pkhu(p0, p1);
        pr.y = pkhu(p2, p3);
        const int gw = ((t << 2) + quad) ^ sw;
        *(int2*)(pw + qs * 1024 + ln15 * 64 + gw * 4) = pr;
      }
    }
    // ---- O += P V
#pragma unroll
    for (int ks = 0; ks < 2; ++ks) {
      short8 vf0 = *(const short8*)(vp + kb + ks * 32);
      short8 vf1 = *(const short8*)(vp + 16 * 4096 + kb + ks * 32);
#pragma unroll
      for (int qs = 0; qs < 2; ++qs) {
        const int g0 = ((ks << 3) + (quad << 1)) ^ sw;
        short8 pf = *(const short8*)(pw + qs * 1024 + ln15 * 64 + g0 * 4);
        acc[qs][0] = __builtin_amdgcn_mfma_f32_16x16x32_bf16(pf, vf0, acc[qs][0], 0, 0, 0);
        acc[qs][1] = __builtin_amdgcn_mfma_f32_16x16x32_bf16(pf, vf1, acc[qs][1], 0, 0, 0);
      }
    }
  };

  for (int kb = 0; kb < 2048; kb += 128) {
    chunk(kb, kfA, kfB, kb + 64);
    chunk(kb + 64, kfB, kfA, (kb + 128) & 2047);
  }

  float lfull[2];
#pragma unroll
  for (int qs = 0; qs < 2; ++qs) {
    float l = lsum[qs];
    l += __shfl_xor(l, 16);
    l += __shfl_xor(l, 32);
    lfull[qs] = l;
  }

  if (half == 1) {
    float* cw = (float*)plds[wv];  // own P region is dead: 32q x 32d fp32
#pragma unroll
    for (int qs = 0; qs < 2; ++qs) {
#pragma unroll
      for (int dg = 0; dg < 2; ++dg)
#pragma unroll
        for (int r = 0; r < 4; ++r)
          cw[(qs * 16 + quad * 4 + r) * 32 + dg * 16 + ln15] = acc[qs][dg][r];
      if (quad == 0) l_up[qt][qs * 16 + ln15] = lfull[qs];
    }
  }
  __syncthreads();
  if (half == 0) {
    const float* cu = (const float*)plds[wv + 2];
#pragma unroll
    for (int qs = 0; qs < 2; ++qs) {
#pragma unroll
      for (int r = 0; r < 4; ++r) {
        const float lown = __shfl(lfull[qs], quad * 4 + r);
        const float lup = l_up[qt][qs * 16 + quad * 4 + r];
        const float rl = 1.0f / (lown + lup);
        const int sg = qb + qs * 16 + quad * 4 + r;
        short* op = O + (size_t)(b * 4096 + sg) * 256 + h * 32 + ln15;
        const int ci = (qs * 16 + quad * 4 + r) * 32 + ln15;
        op[0]  = f2bs((acc[qs][0][r] + cu[ci]) * rl);
        op[16] = f2bs((acc[qs][1][r] + cu[ci + 16]) * rl);
      }
    }
  }
}

// ---------------------------------------------------------------- kernel: proj
// out[b][c][s] = sum_j O[b][s][j] * wp[c][j] + bias[c].
// A = O rows (m=s), B = wp rows (n=c_out). C rows = 4 consecutive s -> f4 store.
__global__ __launch_bounds__(256) void k_proj(
    const short* __restrict__ O, const short* __restrict__ wpb,
    const float* __restrict__ bias, float* __restrict__ out) {
  const int tid = threadIdx.x;
  const int L = tid & 63, wv = tid >> 6;
  const int ln15 = L & 15, quad = L >> 4;
  const int m0 = blockIdx.x * 64 + wv * 16;
  const int n0 = blockIdx.y << 6;
  const int b = m0 >> 12, s0 = m0 & 4095;

  f4 acc[4] = {{0,0,0,0},{0,0,0,0},{0,0,0,0},{0,0,0,0}};
  const short* Ob = O + (size_t)(m0 + ln15) * 256 + quad * 8;
  const short* wb = wpb + (n0 + ln15) * 256 + quad * 8;

#pragma unroll
  for (int cb = 0; cb < 256; cb += 32) {
    short8 af = *(const short8*)(Ob + cb);
#pragma unroll
    for (int sub = 0; sub < 4; ++sub) {
      short8 bfr = *(const short8*)(wb + sub * (16 * 256) + cb);
      acc[sub] = __builtin_amdgcn_mfma_f32_16x16x32_bf16(af, bfr, acc[sub], 0, 0, 0);
    }
  }
#pragma unroll
  for (int sub = 0; sub < 4; ++sub) {
    const int c = n0 + sub * 16 + ln15;
    const float bv = bias[c];
    f4 v;
#pragma unroll
    for (int r = 0; r < 4; ++r) v[r] = acc[sub][r] + bv;
    *(f4*)(out + (size_t)b * (256 * 4096) + (size_t)c * 4096 + s0 + quad * 4) = v;
  }
}

// ---------------------------------------------------------------- launcher
extern "C" void kernel_launch(void* const* d_in, const int* in_sizes, int n_in,
                              void* d_out, int out_size, void* d_ws, size_t ws_size,
                              hipStream_t stream) {
  const float* x      = (const float*)d_in[0];
  const float* w_qkv  = (const float*)d_in[1];
  const float* b_qkv  = (const float*)d_in[2];
  const float* w_proj = (const float*)d_in[3];
  const float* b_proj = (const float*)d_in[4];
  float* out = (float*)d_out;

  const size_t SEG = (size_t)4 * 8 * 4096 * 32;  // 4.19M bf16 elems = 8 MiB
  short* Qr  = (short*)d_ws;
  short* Kq  = Qr + SEG;
  short* Vt  = Kq + SEG;
  short* OX  = Vt + SEG;          // xT (b,s,c) until qkv done, then O (b,s,c)
  short* wqb = OX + SEG;          // 768x256 bf16
  short* wpb = wqb + 768 * 256;   // 256x256 bf16

  k_prep_w<<<256, 256, 0, stream>>>(w_qkv, w_proj, wqb, wpb);
  k_prep_x<<<dim3(64, 4, 4), 256, 0, stream>>>(x, OX);
  k_qkv <<<dim3(256, 12), 256, 0, stream>>>(OX, wqb, b_qkv, Qr, Kq, Vt);
  k_attn<<<dim3(64, 32),  256, 0, stream>>>(Qr, Kq, Vt, OX);
  k_proj<<<dim3(256, 4),  256, 0, stream>>>(OX, wpb, b_proj, out);
}

// Round 6
// 637.527 us; speedup vs baseline: 1.1318x; 1.1318x over previous
//
#include <hip/hip_runtime.h>

// MultiHeadSelfAttention: B=4, C=256, S=4096, heads=8, d=32.
// 5-kernel pipeline, all GEMMs on mfma_f32_16x16x32_bf16, fp32 accumulate.
//   k_prep_w: w_qkv/w_proj fp32 -> bf16
//   k_prep_x: x (b,c,s) fp32 -> xT (b,s,c) bf16 (aliases O buffer)
//   k_qkv : A=w bf16 rows, B=xT rows -> Qr (b,h,S,d) *scale*log2e,
//           Kq (b,h,S,d), Vt (b,h,d,S)
//   k_attn: flash attention, fixed-max softmax, key-split 2x per block.
//           Manually 2x-unrolled K-loop with NAMED double-buffer registers
//           (no arrays/lambdas -> no scratch spill); V + next-K loads issued
//           before compute each half so MFMAs never wait on vmem.
//   k_proj: A=O rows, B=wp rows -> direct coalesced f4 stores (B,C,S)

typedef __attribute__((ext_vector_type(8))) short short8;  // 8 x bf16 MFMA frag
typedef __attribute__((ext_vector_type(4))) float f4;

__device__ __forceinline__ short f2bs(float f) {  // fp32 -> bf16 (RNE)
  union { float f; unsigned u; } v; v.f = f;
  unsigned r = v.u + 0x7FFFu + ((v.u >> 16) & 1u);
  return (short)(r >> 16);
}

__device__ __forceinline__ int pkrne(float a, float b) {  // 2xf32 -> dword RNE
  return (int)((unsigned short)f2bs(a) | ((unsigned)f2bs(b) << 16));
}

// pack hi16(lo+0x8000), hi16(hi+0x8000) -> dword (round-half-up): 3 VALU
__device__ __forceinline__ int pkhu(float lo, float hi) {
  union { float f; unsigned u; } a, b; a.f = lo; b.f = hi;
  return (int)__builtin_amdgcn_perm(b.u + 0x8000u, a.u + 0x8000u, 0x07060302u);
}

// ---------------------------------------------------------------- prep: weights
__global__ __launch_bounds__(256) void k_prep_w(
    const float* __restrict__ wq, const float* __restrict__ wp,
    short* __restrict__ wqb, short* __restrict__ wpb) {
  const int i = blockIdx.x * 256 + threadIdx.x;
  const int NQ = 768 * 256 / 4;
  f4 v; short* dst; int off;
  if (i < NQ) { v = ((const f4*)wq)[i]; dst = wqb; off = i * 4; }
  else        { v = ((const f4*)wp)[i - NQ]; dst = wpb; off = (i - NQ) * 4; }
  int2 pr; pr.x = pkrne(v[0], v[1]); pr.y = pkrne(v[2], v[3]);
  *(int2*)(dst + off) = pr;
}

// ---------------------------------------------------------------- prep: x -> xT
__global__ __launch_bounds__(256) void k_prep_x(
    const float* __restrict__ x, short* __restrict__ xT) {
  const int t = threadIdx.x;
  const int b = blockIdx.z, c0 = blockIdx.y * 64, s0 = blockIdx.x * 64;
  __shared__ __align__(16) short tile[64 * 64];
#pragma unroll
  for (int pass = 0; pass < 4; ++pass) {
    const int cl = pass * 16 + (t >> 4);
    const int sl = (t & 15) * 4;
    f4 v = *(const f4*)(x + ((size_t)(b * 256 + c0 + cl)) * 4096 + s0 + sl);
#pragma unroll
    for (int k = 0; k < 4; ++k) {
      const int s = sl + k;
      tile[s * 64 + (cl ^ ((s & 7) << 3))] = f2bs(v[k]);
    }
  }
  __syncthreads();
#pragma unroll
  for (int i = 0; i < 2; ++i) {
    const int s = t >> 2;
    const int gc = (t & 3) + i * 4;
    const int gg = gc ^ (s & 7);
    short8 row = *(const short8*)(tile + s * 64 + gg * 8);
    *(short8*)(xT + ((size_t)(b * 4096 + s0 + s)) * 256 + c0 + gc * 8) = row;
  }
}

// ---------------------------------------------------------------- kernel: qkv
__global__ __launch_bounds__(256) void k_qkv(
    const short* __restrict__ xT, const short* __restrict__ wqb,
    const float* __restrict__ bias,
    short* __restrict__ Qr, short* __restrict__ Kq, short* __restrict__ Vt) {
  const int tid = threadIdx.x;
  const int L = tid & 63, wv = tid >> 6;
  const int ln15 = L & 15, quad = L >> 4;
  const int mt = blockIdx.x;
  const int b = mt >> 6;
  const int s0 = (mt & 63) << 6;
  const int j0 = blockIdx.y << 6;
  const int jw = j0 + wv * 16;

  __shared__ __align__(16) short tl[4][1024];

  f4 acc[4] = {{0,0,0,0},{0,0,0,0},{0,0,0,0},{0,0,0,0}};
  const short* wb = wqb + (jw + ln15) * 256 + quad * 8;
  const short* xb = xT + (size_t)(b * 4096 + s0 + ln15) * 256 + quad * 8;

#pragma unroll
  for (int cb = 0; cb < 256; cb += 32) {
    short8 af = *(const short8*)(wb + cb);
#pragma unroll
    for (int sub = 0; sub < 4; ++sub) {
      short8 bfr = *(const short8*)(xb + sub * (16 * 256) + cb);
      acc[sub] = __builtin_amdgcn_mfma_f32_16x16x32_bf16(af, bfr, acc[sub], 0, 0, 0);
    }
  }
  float bj[4];
#pragma unroll
  for (int r = 0; r < 4; ++r) bj[r] = bias[jw + quad * 4 + r];

  const int type = j0 >> 8;  // 0=Q 1=K 2=V
  const int hj = jw & 255;
  const int bh = b * 8 + (hj >> 5);
  const int db = hj & 31;

  if (type != 2) {
    const float qsc = 0.17677669529663689f * 1.44269504088896f;
    const float mul = (type == 0) ? qsc : 1.0f;
    short* dst = (type == 0) ? Qr : Kq;
#pragma unroll
    for (int sub = 0; sub < 4; ++sub) {
      float v0 = (acc[sub][0] + bj[0]) * mul;
      float v1 = (acc[sub][1] + bj[1]) * mul;
      float v2 = (acc[sub][2] + bj[2]) * mul;
      float v3 = (acc[sub][3] + bj[3]) * mul;
      int2 pr; pr.x = pkhu(v0, v1); pr.y = pkhu(v2, v3);
      *(int2*)(dst + (size_t)(bh * 4096 + s0 + sub * 16 + ln15) * 32 + db + quad * 4) = pr;
    }
  } else {
    short* tv = tl[wv];
#pragma unroll
    for (int sub = 0; sub < 4; ++sub) {
      const int s = sub * 16 + ln15;
#pragma unroll
      for (int r = 0; r < 4; ++r) {
        const int dl = quad * 4 + r;
        tv[dl * 64 + ((((s >> 3) ^ dl) & 7) << 3) + (s & 7)] = f2bs(acc[sub][r] + bj[r]);
      }
    }
#pragma unroll
    for (int i = 0; i < 2; ++i) {
      const int dl = i * 8 + (L >> 3);
      const int gs = L & 7;
      const int gg = gs ^ (dl & 7);
      short8 row = *(const short8*)(tv + dl * 64 + gg * 8);
      *(short8*)(Vt + (size_t)(bh * 32 + db + dl) * 4096 + s0 + gs * 8) = row;
    }
  }
}

// ---------------------------------------------------------------- kernel: attn
// Block = 4 waves: wave wv -> q-tile (wv&1), key-half (wv>>1).
// Manually 2x-unrolled 64-key chunks with named K double-buffer registers.
// Per half: issue V(ks0)+next-K loads, QK x8 -> exp2 -> pack -> ds_write_b64,
// PV ks0, load V(ks1), PV ks1.

#define QKT(KF, TT)                                                          \
  {                                                                          \
    f4 sc0 = __builtin_amdgcn_mfma_f32_16x16x32_bf16(KF, qf0, z4, 0, 0, 0);  \
    float a0 = __builtin_amdgcn_exp2f(sc0[0]);                               \
    float a1 = __builtin_amdgcn_exp2f(sc0[1]);                               \
    float a2 = __builtin_amdgcn_exp2f(sc0[2]);                               \
    float a3 = __builtin_amdgcn_exp2f(sc0[3]);                               \
    ls0 += (a0 + a1) + (a2 + a3);                                            \
    int2 w0; w0.x = pkhu(a0, a1); w0.y = pkhu(a2, a3);                       \
    *(int2*)(pw + ln15 * 64 + ((((TT) << 2) + quad) ^ sw) * 4) = w0;         \
    f4 sc1 = __builtin_amdgcn_mfma_f32_16x16x32_bf16(KF, qf1, z4, 0, 0, 0);  \
    float b0 = __builtin_amdgcn_exp2f(sc1[0]);                               \
    float b1 = __builtin_amdgcn_exp2f(sc1[1]);                               \
    float b2 = __builtin_amdgcn_exp2f(sc1[2]);                               \
    float b3 = __builtin_amdgcn_exp2f(sc1[3]);                               \
    ls1 += (b0 + b1) + (b2 + b3);                                            \
    int2 w1; w1.x = pkhu(b0, b1); w1.y = pkhu(b2, b3);                       \
    *(int2*)(pw + 1024 + ln15 * 64 + ((((TT) << 2) + quad) ^ sw) * 4) = w1;  \
  }

#define PVK(KS, VA, VB)                                                      \
  {                                                                          \
    const int g0 = (((KS) << 3) + (quad << 1)) ^ sw;                         \
    short8 pf0 = *(const short8*)(pw + ln15 * 64 + g0 * 4);                  \
    short8 pf1 = *(const short8*)(pw + 1024 + ln15 * 64 + g0 * 4);           \
    acc00 = __builtin_amdgcn_mfma_f32_16x16x32_bf16(pf0, VA, acc00, 0, 0, 0);\
    acc01 = __builtin_amdgcn_mfma_f32_16x16x32_bf16(pf0, VB, acc01, 0, 0, 0);\
    acc10 = __builtin_amdgcn_mfma_f32_16x16x32_bf16(pf1, VA, acc10, 0, 0, 0);\
    acc11 = __builtin_amdgcn_mfma_f32_16x16x32_bf16(pf1, VB, acc11, 0, 0, 0);\
  }

#define ATTN_HALF(KC0, KC1, KC2, KC3, KN0, KN1, KN2, KN3, KCUR, KNEXT)       \
  {                                                                          \
    const short* vpc = vp + (KCUR);                                          \
    const short* vpc1 = vp1 + (KCUR);                                        \
    short8 vf00 = *(const short8*)(vpc);                                     \
    short8 vf10 = *(const short8*)(vpc1);                                    \
    const short* nkp = kp + (KNEXT) * 32;                                    \
    KN0 = *(const short8*)(nkp);                                             \
    KN1 = *(const short8*)(nkp + 512);                                       \
    KN2 = *(const short8*)(nkp + 1024);                                      \
    KN3 = *(const short8*)(nkp + 1536);                                      \
    QKT(KC0, 0) QKT(KC1, 1) QKT(KC2, 2) QKT(KC3, 3)                          \
    PVK(0, vf00, vf10)                                                       \
    short8 vf01 = *(const short8*)(vpc + 32);                                \
    short8 vf11 = *(const short8*)(vpc1 + 32);                               \
    PVK(1, vf01, vf11)                                                       \
  }

__global__ __launch_bounds__(256, 6) void k_attn(
    const short* __restrict__ Qr, const short* __restrict__ Kq,
    const short* __restrict__ Vt, short* __restrict__ O) {
  const int tid = threadIdx.x;
  const int L = tid & 63, wv = tid >> 6;
  const int ln15 = L & 15, quad = L >> 4;
  const int bh = blockIdx.y;
  const int b = bh >> 3, h = bh & 7;
  const int qt = wv & 1, half = wv >> 1;
  const int qb = blockIdx.x * 64 + qt * 32;

  const short* Qb = Qr + (size_t)bh * 4096 * 32;
  const short* Kb = Kq + (size_t)bh * 4096 * 32 + half * 2048 * 32;
  const short* Vb = Vt + (size_t)bh * 32 * 4096 + half * 2048;

  __shared__ __align__(16) short plds[4][2048];
  __shared__ float l_up[2][32];
  short* pw = plds[wv];
  const int sw = ln15 & 14;

  short8 qf0 = *(const short8*)(Qb + (qb + ln15) * 32 + quad * 8);
  short8 qf1 = *(const short8*)(Qb + (qb + 16 + ln15) * 32 + quad * 8);

  f4 acc00 = {0,0,0,0}, acc01 = {0,0,0,0}, acc10 = {0,0,0,0}, acc11 = {0,0,0,0};
  float ls0 = 0.f, ls1 = 0.f;
  const f4 z4 = {0.f, 0.f, 0.f, 0.f};

  const short* kp = Kb + ln15 * 32 + quad * 8;
  const short* vp = Vb + ln15 * 4096 + quad * 8;
  const short* vp1 = vp + 16 * 4096;

  short8 ka0 = *(const short8*)(kp);
  short8 ka1 = *(const short8*)(kp + 512);
  short8 ka2 = *(const short8*)(kp + 1024);
  short8 ka3 = *(const short8*)(kp + 1536);
  short8 kb0, kb1, kb2, kb3;

  for (int kpos = 0; kpos < 2048; kpos += 128) {
    ATTN_HALF(ka0, ka1, ka2, ka3, kb0, kb1, kb2, kb3, kpos, kpos + 64)
    const int knext = (kpos + 128) & 2047;  // dummy wrap load on last iter
    ATTN_HALF(kb0, kb1, kb2, kb3, ka0, ka1, ka2, ka3, kpos + 64, knext)
  }

  float lf0 = ls0, lf1 = ls1;
  lf0 += __shfl_xor(lf0, 16); lf0 += __shfl_xor(lf0, 32);
  lf1 += __shfl_xor(lf1, 16); lf1 += __shfl_xor(lf1, 32);

  if (half == 1) {
    float* cw = (float*)plds[wv];  // own P region dead: 32q x 32d fp32
#pragma unroll
    for (int r = 0; r < 4; ++r) {
      cw[(quad * 4 + r) * 32 + ln15]           = acc00[r];
      cw[(quad * 4 + r) * 32 + 16 + ln15]      = acc01[r];
      cw[(16 + quad * 4 + r) * 32 + ln15]      = acc10[r];
      cw[(16 + quad * 4 + r) * 32 + 16 + ln15] = acc11[r];
    }
    if (quad == 0) { l_up[qt][ln15] = lf0; l_up[qt][16 + ln15] = lf1; }
  }
  __syncthreads();
  if (half == 0) {
    const float* cu = (const float*)plds[wv + 2];
#pragma unroll
    for (int r = 0; r < 4; ++r) {
      {
        const float lown = __shfl(lf0, quad * 4 + r);
        const float lup = l_up[qt][quad * 4 + r];
        const float rl = 1.0f / (lown + lup);
        const int sg = qb + quad * 4 + r;
        short* op = O + (size_t)(b * 4096 + sg) * 256 + h * 32 + ln15;
        const int ci = (quad * 4 + r) * 32 + ln15;
        op[0]  = f2bs((acc00[r] + cu[ci]) * rl);
        op[16] = f2bs((acc01[r] + cu[ci + 16]) * rl);
      }
      {
        const float lown = __shfl(lf1, quad * 4 + r);
        const float lup = l_up[qt][16 + quad * 4 + r];
        const float rl = 1.0f / (lown + lup);
        const int sg = qb + 16 + quad * 4 + r;
        short* op = O + (size_t)(b * 4096 + sg) * 256 + h * 32 + ln15;
        const int ci = (16 + quad * 4 + r) * 32 + ln15;
        op[0]  = f2bs((acc10[r] + cu[ci]) * rl);
        op[16] = f2bs((acc11[r] + cu[ci + 16]) * rl);
      }
    }
  }
}

// ---------------------------------------------------------------- kernel: proj
__global__ __launch_bounds__(256) void k_proj(
    const short* __restrict__ O, const short* __restrict__ wpb,
    const float* __restrict__ bias, float* __restrict__ out) {
  const int tid = threadIdx.x;
  const int L = tid & 63, wv = tid >> 6;
  const int ln15 = L & 15, quad = L >> 4;
  const int m0 = blockIdx.x * 64 + wv * 16;
  const int n0 = blockIdx.y << 6;
  const int b = m0 >> 12, s0 = m0 & 4095;

  f4 acc[4] = {{0,0,0,0},{0,0,0,0},{0,0,0,0},{0,0,0,0}};
  const short* Ob = O + (size_t)(m0 + ln15) * 256 + quad * 8;
  const short* wb = wpb + (n0 + ln15) * 256 + quad * 8;

#pragma unroll
  for (int cb = 0; cb < 256; cb += 32) {
    short8 af = *(const short8*)(Ob + cb);
#pragma unroll
    for (int sub = 0; sub < 4; ++sub) {
      short8 bfr = *(const short8*)(wb + sub * (16 * 256) + cb);
      acc[sub] = __builtin_amdgcn_mfma_f32_16x16x32_bf16(af, bfr, acc[sub], 0, 0, 0);
    }
  }
#pragma unroll
  for (int sub = 0; sub < 4; ++sub) {
    const int c = n0 + sub * 16 + ln15;
    const float bv = bias[c];
    f4 v;
#pragma unroll
    for (int r = 0; r < 4; ++r) v[r] = acc[sub][r] + bv;
    *(f4*)(out + (size_t)b * (256 * 4096) + (size_t)c * 4096 + s0 + quad * 4) = v;
  }
}

// ---------------------------------------------------------------- launcher
extern "C" void kernel_launch(void* const* d_in, const int* in_sizes, int n_in,
                              void* d_out, int out_size, void* d_ws, size_t ws_size,
                              hipStream_t stream) {
  const float* x      = (const float*)d_in[0];
  const float* w_qkv  = (const float*)d_in[1];
  const float* b_qkv  = (const float*)d_in[2];
  const float* w_proj = (const float*)d_in[3];
  const float* b_proj = (const float*)d_in[4];
  float* out = (float*)d_out;

  const size_t SEG = (size_t)4 * 8 * 4096 * 32;  // 4.19M bf16 elems = 8 MiB
  short* Qr  = (short*)d_ws;
  short* Kq  = Qr + SEG;
  short* Vt  = Kq + SEG;
  short* OX  = Vt + SEG;          // xT (b,s,c) until qkv done, then O (b,s,c)
  short* wqb = OX + SEG;
  short* wpb = wqb + 768 * 256;

  k_prep_w<<<256, 256, 0, stream>>>(w_qkv, w_proj, wqb, wpb);
  k_prep_x<<<dim3(64, 4, 4), 256, 0, stream>>>(x, OX);
  k_qkv <<<dim3(256, 12), 256, 0, stream>>>(OX, wqb, b_qkv, Qr, Kq, Vt);
  k_attn<<<dim3(64, 32),  256, 0, stream>>>(Qr, Kq, Vt, OX);
  k_proj<<<dim3(256, 4),  256, 0, stream>>>(OX, wpb, b_proj, out);
}

// Round 7
// 366.318 us; speedup vs baseline: 1.9697x; 1.7404x over previous
//
#include <hip/hip_runtime.h>

// MultiHeadSelfAttention: B=4, C=256, S=4096, heads=8, d=32.
// 5-kernel pipeline, all GEMMs on mfma_f32_16x16x32_bf16, fp32 accumulate.
//   k_prep_w: w_qkv/w_proj fp32 -> bf16
//   k_prep_x: x (b,c,s) fp32 -> xT (b,s,c) bf16 (aliases O buffer)
//   k_qkv : A=w bf16 rows, B=xT rows -> Qr (b,h,S,d) *scale*log2e,
//           Kq (b,h,S,d), Vt (b,h,d,S)
//   k_attn: flash attention, fixed-max softmax, key-split 2x per block.
//           R4 structure (plain loop, inline K loads — compiler schedules;
//           explicit prefetch regressed to scratch spill in R5/R6) with
//           __launch_bounds__(256,6) for VGPR headroom (no accvgpr moves).
//   k_proj: A=O rows, B=wp rows -> direct coalesced f4 stores (B,C,S)

typedef __attribute__((ext_vector_type(8))) short short8;  // 8 x bf16 MFMA frag
typedef __attribute__((ext_vector_type(4))) float f4;

__device__ __forceinline__ short f2bs(float f) {  // fp32 -> bf16 (RNE)
  union { float f; unsigned u; } v; v.f = f;
  unsigned r = v.u + 0x7FFFu + ((v.u >> 16) & 1u);
  return (short)(r >> 16);
}

__device__ __forceinline__ int pkrne(float a, float b) {  // 2xf32 -> dword RNE
  return (int)((unsigned short)f2bs(a) | ((unsigned)f2bs(b) << 16));
}

// pack hi16(lo+0x8000), hi16(hi+0x8000) -> dword (round-half-up): 3 VALU
__device__ __forceinline__ int pkhu(float lo, float hi) {
  union { float f; unsigned u; } a, b; a.f = lo; b.f = hi;
  return (int)__builtin_amdgcn_perm(b.u + 0x8000u, a.u + 0x8000u, 0x07060302u);
}

// ---------------------------------------------------------------- prep: weights
__global__ __launch_bounds__(256) void k_prep_w(
    const float* __restrict__ wq, const float* __restrict__ wp,
    short* __restrict__ wqb, short* __restrict__ wpb) {
  const int i = blockIdx.x * 256 + threadIdx.x;
  const int NQ = 768 * 256 / 4;
  f4 v; short* dst; int off;
  if (i < NQ) { v = ((const f4*)wq)[i]; dst = wqb; off = i * 4; }
  else        { v = ((const f4*)wp)[i - NQ]; dst = wpb; off = (i - NQ) * 4; }
  int2 pr; pr.x = pkrne(v[0], v[1]); pr.y = pkrne(v[2], v[3]);
  *(int2*)(dst + off) = pr;
}

// ---------------------------------------------------------------- prep: x -> xT
__global__ __launch_bounds__(256) void k_prep_x(
    const float* __restrict__ x, short* __restrict__ xT) {
  const int t = threadIdx.x;
  const int b = blockIdx.z, c0 = blockIdx.y * 64, s0 = blockIdx.x * 64;
  __shared__ __align__(16) short tile[64 * 64];
#pragma unroll
  for (int pass = 0; pass < 4; ++pass) {
    const int cl = pass * 16 + (t >> 4);
    const int sl = (t & 15) * 4;
    f4 v = *(const f4*)(x + ((size_t)(b * 256 + c0 + cl)) * 4096 + s0 + sl);
#pragma unroll
    for (int k = 0; k < 4; ++k) {
      const int s = sl + k;
      tile[s * 64 + (cl ^ ((s & 7) << 3))] = f2bs(v[k]);
    }
  }
  __syncthreads();
#pragma unroll
  for (int i = 0; i < 2; ++i) {
    const int s = t >> 2;
    const int gc = (t & 3) + i * 4;
    const int gg = gc ^ (s & 7);
    short8 row = *(const short8*)(tile + s * 64 + gg * 8);
    *(short8*)(xT + ((size_t)(b * 4096 + s0 + s)) * 256 + c0 + gc * 8) = row;
  }
}

// ---------------------------------------------------------------- kernel: qkv
__global__ __launch_bounds__(256) void k_qkv(
    const short* __restrict__ xT, const short* __restrict__ wqb,
    const float* __restrict__ bias,
    short* __restrict__ Qr, short* __restrict__ Kq, short* __restrict__ Vt) {
  const int tid = threadIdx.x;
  const int L = tid & 63, wv = tid >> 6;
  const int ln15 = L & 15, quad = L >> 4;
  const int mt = blockIdx.x;
  const int b = mt >> 6;
  const int s0 = (mt & 63) << 6;
  const int j0 = blockIdx.y << 6;
  const int jw = j0 + wv * 16;

  __shared__ __align__(16) short tl[4][1024];

  f4 acc[4] = {{0,0,0,0},{0,0,0,0},{0,0,0,0},{0,0,0,0}};
  const short* wb = wqb + (jw + ln15) * 256 + quad * 8;
  const short* xb = xT + (size_t)(b * 4096 + s0 + ln15) * 256 + quad * 8;

#pragma unroll
  for (int cb = 0; cb < 256; cb += 32) {
    short8 af = *(const short8*)(wb + cb);
#pragma unroll
    for (int sub = 0; sub < 4; ++sub) {
      short8 bfr = *(const short8*)(xb + sub * (16 * 256) + cb);
      acc[sub] = __builtin_amdgcn_mfma_f32_16x16x32_bf16(af, bfr, acc[sub], 0, 0, 0);
    }
  }
  float bj[4];
#pragma unroll
  for (int r = 0; r < 4; ++r) bj[r] = bias[jw + quad * 4 + r];

  const int type = j0 >> 8;  // 0=Q 1=K 2=V
  const int hj = jw & 255;
  const int bh = b * 8 + (hj >> 5);
  const int db = hj & 31;

  if (type != 2) {
    const float qsc = 0.17677669529663689f * 1.44269504088896f;
    const float mul = (type == 0) ? qsc : 1.0f;
    short* dst = (type == 0) ? Qr : Kq;
#pragma unroll
    for (int sub = 0; sub < 4; ++sub) {
      float v0 = (acc[sub][0] + bj[0]) * mul;
      float v1 = (acc[sub][1] + bj[1]) * mul;
      float v2 = (acc[sub][2] + bj[2]) * mul;
      float v3 = (acc[sub][3] + bj[3]) * mul;
      int2 pr; pr.x = pkhu(v0, v1); pr.y = pkhu(v2, v3);
      *(int2*)(dst + (size_t)(bh * 4096 + s0 + sub * 16 + ln15) * 32 + db + quad * 4) = pr;
    }
  } else {
    short* tv = tl[wv];
#pragma unroll
    for (int sub = 0; sub < 4; ++sub) {
      const int s = sub * 16 + ln15;
#pragma unroll
      for (int r = 0; r < 4; ++r) {
        const int dl = quad * 4 + r;
        tv[dl * 64 + ((((s >> 3) ^ dl) & 7) << 3) + (s & 7)] = f2bs(acc[sub][r] + bj[r]);
      }
    }
#pragma unroll
    for (int i = 0; i < 2; ++i) {
      const int dl = i * 8 + (L >> 3);
      const int gs = L & 7;
      const int gg = gs ^ (dl & 7);
      short8 row = *(const short8*)(tv + dl * 64 + gg * 8);
      *(short8*)(Vt + (size_t)(bh * 32 + db + dl) * 4096 + s0 + gs * 8) = row;
    }
  }
}

// ---------------------------------------------------------------- kernel: attn
// Block = 4 waves: wave wv -> q-tile (wv&1), key-half (wv>>1).
// Per 64-key chunk: QK (A=K m=key, B=Q n=q) -> exp2 -> round-half-up pack ->
// ds_write_b64 ; PV (A=P b128 LDS reads, B=Vt direct b128).
// Plain loop — compiler schedules loads; (256,6) gives register headroom so
// MFMA results live in plain VGPRs (no accvgpr round-trip for exp2).
__global__ __launch_bounds__(256, 6) void k_attn(
    const short* __restrict__ Qr, const short* __restrict__ Kq,
    const short* __restrict__ Vt, short* __restrict__ O) {
  const int tid = threadIdx.x;
  const int L = tid & 63, wv = tid >> 6;
  const int ln15 = L & 15, quad = L >> 4;
  const int bh = blockIdx.y;
  const int b = bh >> 3, h = bh & 7;
  const int qt = wv & 1, half = wv >> 1;
  const int qb = blockIdx.x * 64 + qt * 32;

  const short* Qb = Qr + (size_t)bh * 4096 * 32;
  const short* Kb = Kq + (size_t)bh * 4096 * 32 + half * 2048 * 32;
  const short* Vb = Vt + (size_t)bh * 32 * 4096 + half * 2048;

  __shared__ __align__(16) short plds[4][2048];  // per-wave P (2 qs x 16q x 64k)
  __shared__ float l_up[2][32];
  short* pw = plds[wv];
  const int sw = ln15 & 14;  // granule xor-swizzle (even -> keeps b128 pairs)

  short8 qf[2];
#pragma unroll
  for (int qs = 0; qs < 2; ++qs)
    qf[qs] = *(const short8*)(Qb + (qb + qs * 16 + ln15) * 32 + quad * 8);

  f4 acc[2][2] = {{{0,0,0,0},{0,0,0,0}},{{0,0,0,0},{0,0,0,0}}};
  float lsum[2] = {0.f, 0.f};
  const f4 z4 = {0.f, 0.f, 0.f, 0.f};

  const short* kp = Kb + ln15 * 32 + quad * 8;
  const short* vp = Vb + ln15 * 4096 + quad * 8;

  for (int kb = 0; kb < 2048; kb += 64) {
    // ---- S = K Q^T, exp2, pack (round-half-up), one b64 write per (t,qs)
#pragma unroll
    for (int t = 0; t < 4; ++t) {
      short8 kf = *(const short8*)(kp + (kb + t * 16) * 32);
#pragma unroll
      for (int qs = 0; qs < 2; ++qs) {
        f4 sc = __builtin_amdgcn_mfma_f32_16x16x32_bf16(kf, qf[qs], z4, 0, 0, 0);
        float p0 = __builtin_amdgcn_exp2f(sc[0]);
        float p1 = __builtin_amdgcn_exp2f(sc[1]);
        float p2 = __builtin_amdgcn_exp2f(sc[2]);
        float p3 = __builtin_amdgcn_exp2f(sc[3]);
        lsum[qs] += (p0 + p1) + (p2 + p3);
        int2 pr;
        pr.x = pkhu(p0, p1);
        pr.y = pkhu(p2, p3);
        const int gw = ((t << 2) + quad) ^ sw;
        *(int2*)(pw + qs * 1024 + ln15 * 64 + gw * 4) = pr;
      }
    }
    // ---- O += P V   (A = P b128 reads, B = Vt direct b128)
#pragma unroll
    for (int ks = 0; ks < 2; ++ks) {
      short8 vf0 = *(const short8*)(vp + kb + ks * 32);
      short8 vf1 = *(const short8*)(vp + 16 * 4096 + kb + ks * 32);
#pragma unroll
      for (int qs = 0; qs < 2; ++qs) {
        const int g0 = ((ks << 3) + (quad << 1)) ^ sw;
        short8 pf = *(const short8*)(pw + qs * 1024 + ln15 * 64 + g0 * 4);
        acc[qs][0] = __builtin_amdgcn_mfma_f32_16x16x32_bf16(pf, vf0, acc[qs][0], 0, 0, 0);
        acc[qs][1] = __builtin_amdgcn_mfma_f32_16x16x32_bf16(pf, vf1, acc[qs][1], 0, 0, 0);
      }
    }
  }

  float lfull[2];
#pragma unroll
  for (int qs = 0; qs < 2; ++qs) {
    float l = lsum[qs];
    l += __shfl_xor(l, 16);
    l += __shfl_xor(l, 32);
    lfull[qs] = l;
  }

  if (half == 1) {
    float* cw = (float*)plds[wv];  // own P region dead: 32q x 32d fp32
#pragma unroll
    for (int qs = 0; qs < 2; ++qs) {
#pragma unroll
      for (int dg = 0; dg < 2; ++dg)
#pragma unroll
        for (int r = 0; r < 4; ++r)
          cw[(qs * 16 + quad * 4 + r) * 32 + dg * 16 + ln15] = acc[qs][dg][r];
      if (quad == 0) l_up[qt][qs * 16 + ln15] = lfull[qs];
    }
  }
  __syncthreads();
  if (half == 0) {
    const float* cu = (const float*)plds[wv + 2];
#pragma unroll
    for (int qs = 0; qs < 2; ++qs) {
#pragma unroll
      for (int r = 0; r < 4; ++r) {
        const float lown = __shfl(lfull[qs], quad * 4 + r);
        const float lup = l_up[qt][qs * 16 + quad * 4 + r];
        const float rl = 1.0f / (lown + lup);
        const int sg = qb + qs * 16 + quad * 4 + r;
        short* op = O + (size_t)(b * 4096 + sg) * 256 + h * 32 + ln15;
        const int ci = (qs * 16 + quad * 4 + r) * 32 + ln15;
        op[0]  = f2bs((acc[qs][0][r] + cu[ci]) * rl);
        op[16] = f2bs((acc[qs][1][r] + cu[ci + 16]) * rl);
      }
    }
  }
}

// ---------------------------------------------------------------- kernel: proj
__global__ __launch_bounds__(256) void k_proj(
    const short* __restrict__ O, const short* __restrict__ wpb,
    const float* __restrict__ bias, float* __restrict__ out) {
  const int tid = threadIdx.x;
  const int L = tid & 63, wv = tid >> 6;
  const int ln15 = L & 15, quad = L >> 4;
  const int m0 = blockIdx.x * 64 + wv * 16;
  const int n0 = blockIdx.y << 6;
  const int b = m0 >> 12, s0 = m0 & 4095;

  f4 acc[4] = {{0,0,0,0},{0,0,0,0},{0,0,0,0},{0,0,0,0}};
  const short* Ob = O + (size_t)(m0 + ln15) * 256 + quad * 8;
  const short* wb = wpb + (n0 + ln15) * 256 + quad * 8;

#pragma unroll
  for (int cb = 0; cb < 256; cb += 32) {
    short8 af = *(const short8*)(Ob + cb);
#pragma unroll
    for (int sub = 0; sub < 4; ++sub) {
      short8 bfr = *(const short8*)(wb + sub * (16 * 256) + cb);
      acc[sub] = __builtin_amdgcn_mfma_f32_16x16x32_bf16(af, bfr, acc[sub], 0, 0, 0);
    }
  }
#pragma unroll
  for (int sub = 0; sub < 4; ++sub) {
    const int c = n0 + sub * 16 + ln15;
    const float bv = bias[c];
    f4 v;
#pragma unroll
    for (int r = 0; r < 4; ++r) v[r] = acc[sub][r] + bv;
    *(f4*)(out + (size_t)b * (256 * 4096) + (size_t)c * 4096 + s0 + quad * 4) = v;
  }
}

// ---------------------------------------------------------------- launcher
extern "C" void kernel_launch(void* const* d_in, const int* in_sizes, int n_in,
                              void* d_out, int out_size, void* d_ws, size_t ws_size,
                              hipStream_t stream) {
  const float* x      = (const float*)d_in[0];
  const float* w_qkv  = (const float*)d_in[1];
  const float* b_qkv  = (const float*)d_in[2];
  const float* w_proj = (const float*)d_in[3];
  const float* b_proj = (const float*)d_in[4];
  float* out = (float*)d_out;

  const size_t SEG = (size_t)4 * 8 * 4096 * 32;  // 4.19M bf16 elems = 8 MiB
  short* Qr  = (short*)d_ws;
  short* Kq  = Qr + SEG;
  short* Vt  = Kq + SEG;
  short* OX  = Vt + SEG;          // xT (b,s,c) until qkv done, then O (b,s,c)
  short* wqb = OX + SEG;
  short* wpb = wqb + 768 * 256;

  k_prep_w<<<256, 256, 0, stream>>>(w_qkv, w_proj, wqb, wpb);
  k_prep_x<<<dim3(64, 4, 4), 256, 0, stream>>>(x, OX);
  k_qkv <<<dim3(256, 12), 256, 0, stream>>>(OX, wqb, b_qkv, Qr, Kq, Vt);
  k_attn<<<dim3(64, 32),  256, 0, stream>>>(Qr, Kq, Vt, OX);
  k_proj<<<dim3(256, 4),  256, 0, stream>>>(OX, wpb, b_proj, out);
}

// Round 8
// 332.456 us; speedup vs baseline: 2.1704x; 1.1019x over previous
//
#include <hip/hip_runtime.h>

// MultiHeadSelfAttention: B=4, C=256, S=4096, heads=8, d=32.
// 5-kernel pipeline. k_attn uses 32x32x16 MFMAs with a register-direct
// QK->softmax->PV path: QK C-layout (A=K m=key, B=Q n=q) feeds PV's B operand
// (B=P) with NO data movement -- C reg j+8p == PV-half-p B reg j under key
// permutation phi(16p+8h+j)=16p+4h+(j&3)+8*(j>>2), which is absorbed by
// storing V column-permuted (4-chunk order [0,2,1,3] per 16-key group).
// Main attention loop touches no LDS at all.

typedef __attribute__((ext_vector_type(8))) short short8;   // 8 x bf16 frag
typedef __attribute__((ext_vector_type(4))) float f4;
typedef __attribute__((ext_vector_type(16))) float f16v;    // 32x32 C/D

__device__ __forceinline__ short f2bs(float f) {  // fp32 -> bf16 (RNE)
  union { float f; unsigned u; } v; v.f = f;
  unsigned r = v.u + 0x7FFFu + ((v.u >> 16) & 1u);
  return (short)(r >> 16);
}

__device__ __forceinline__ int pkrne(float a, float b) {
  return (int)((unsigned short)f2bs(a) | ((unsigned)f2bs(b) << 16));
}

// pack hi16(lo+0x8000), hi16(hi+0x8000) -> dword (round-half-up): 3 VALU
__device__ __forceinline__ int pkhu(float lo, float hi) {
  union { float f; unsigned u; } a, b; a.f = lo; b.f = hi;
  return (int)__builtin_amdgcn_perm(b.u + 0x8000u, a.u + 0x8000u, 0x07060302u);
}

__device__ __forceinline__ short8 mk8(int a, int b, int c, int d) {
  int4 t; t.x = a; t.y = b; t.z = c; t.w = d;
  short8 r; __builtin_memcpy(&r, &t, 16); return r;
}

// ---------------------------------------------------------------- prep: weights
__global__ __launch_bounds__(256) void k_prep_w(
    const float* __restrict__ wq, const float* __restrict__ wp,
    short* __restrict__ wqb, short* __restrict__ wpb) {
  const int i = blockIdx.x * 256 + threadIdx.x;
  const int NQ = 768 * 256 / 4;
  f4 v; short* dst; int off;
  if (i < NQ) { v = ((const f4*)wq)[i]; dst = wqb; off = i * 4; }
  else        { v = ((const f4*)wp)[i - NQ]; dst = wpb; off = (i - NQ) * 4; }
  int2 pr; pr.x = pkrne(v[0], v[1]); pr.y = pkrne(v[2], v[3]);
  *(int2*)(dst + off) = pr;
}

// ---------------------------------------------------------------- prep: x -> xT
__global__ __launch_bounds__(256) void k_prep_x(
    const float* __restrict__ x, short* __restrict__ xT) {
  const int t = threadIdx.x;
  const int b = blockIdx.z, c0 = blockIdx.y * 64, s0 = blockIdx.x * 64;
  __shared__ __align__(16) short tile[64 * 64];
#pragma unroll
  for (int pass = 0; pass < 4; ++pass) {
    const int cl = pass * 16 + (t >> 4);
    const int sl = (t & 15) * 4;
    f4 v = *(const f4*)(x + ((size_t)(b * 256 + c0 + cl)) * 4096 + s0 + sl);
#pragma unroll
    for (int k = 0; k < 4; ++k) {
      const int s = sl + k;
      tile[s * 64 + (cl ^ ((s & 7) << 3))] = f2bs(v[k]);
    }
  }
  __syncthreads();
#pragma unroll
  for (int i = 0; i < 2; ++i) {
    const int s = t >> 2;
    const int gc = (t & 3) + i * 4;
    const int gg = gc ^ (s & 7);
    short8 row = *(const short8*)(tile + s * 64 + gg * 8);
    *(short8*)(xT + ((size_t)(b * 4096 + s0 + s)) * 256 + c0 + gc * 8) = row;
  }
}

// ---------------------------------------------------------------- kernel: qkv
__global__ __launch_bounds__(256) void k_qkv(
    const short* __restrict__ xT, const short* __restrict__ wqb,
    const float* __restrict__ bias,
    short* __restrict__ Qr, short* __restrict__ Kq, short* __restrict__ Vp) {
  const int tid = threadIdx.x;
  const int L = tid & 63, wv = tid >> 6;
  const int ln15 = L & 15, quad = L >> 4;
  const int mt = blockIdx.x;
  const int b = mt >> 6;
  const int s0 = (mt & 63) << 6;
  const int j0 = blockIdx.y << 6;
  const int jw = j0 + wv * 16;

  __shared__ __align__(16) short tl[4][1024];

  f4 acc[4] = {{0,0,0,0},{0,0,0,0},{0,0,0,0},{0,0,0,0}};
  const short* wb = wqb + (jw + ln15) * 256 + quad * 8;
  const short* xb = xT + (size_t)(b * 4096 + s0 + ln15) * 256 + quad * 8;

#pragma unroll
  for (int cb = 0; cb < 256; cb += 32) {
    short8 af = *(const short8*)(wb + cb);
#pragma unroll
    for (int sub = 0; sub < 4; ++sub) {
      short8 bfr = *(const short8*)(xb + sub * (16 * 256) + cb);
      acc[sub] = __builtin_amdgcn_mfma_f32_16x16x32_bf16(af, bfr, acc[sub], 0, 0, 0);
    }
  }
  float bj[4];
#pragma unroll
  for (int r = 0; r < 4; ++r) bj[r] = bias[jw + quad * 4 + r];

  const int type = j0 >> 8;  // 0=Q 1=K 2=V
  const int hj = jw & 255;
  const int bh = b * 8 + (hj >> 5);
  const int db = hj & 31;

  if (type != 2) {
    const float qsc = 0.17677669529663689f * 1.44269504088896f;
    const float mul = (type == 0) ? qsc : 1.0f;
    short* dst = (type == 0) ? Qr : Kq;
#pragma unroll
    for (int sub = 0; sub < 4; ++sub) {
      float v0 = (acc[sub][0] + bj[0]) * mul;
      float v1 = (acc[sub][1] + bj[1]) * mul;
      float v2 = (acc[sub][2] + bj[2]) * mul;
      float v3 = (acc[sub][3] + bj[3]) * mul;
      int2 pr; pr.x = pkhu(v0, v1); pr.y = pkhu(v2, v3);
      *(int2*)(dst + (size_t)(bh * 4096 + s0 + sub * 16 + ln15) * 32 + db + quad * 4) = pr;
    }
  } else {
    // V: transpose to (d, s) through per-wave LDS, then store with the
    // PV-A-frag column permutation: within each 16-key group, 4-chunk
    // order [0,2,1,3] (self-inverse).
    short* tv = tl[wv];
#pragma unroll
    for (int sub = 0; sub < 4; ++sub) {
      const int s = sub * 16 + ln15;
#pragma unroll
      for (int r = 0; r < 4; ++r) {
        const int dl = quad * 4 + r;
        tv[dl * 64 + ((((s >> 3) ^ dl) & 7) << 3) + (s & 7)] = f2bs(acc[sub][r] + bj[r]);
      }
    }
#pragma unroll
    for (int i = 0; i < 2; ++i) {
      const int dl = i * 8 + (L >> 3);
      const int gs = L & 7;
      const int gg = gs ^ (dl & 7);
      short8 row = *(const short8*)(tv + dl * 64 + gg * 8);
      union { short8 s; int4 i4; } u; u.s = row;
      short* vrow = Vp + (size_t)(bh * 32 + db + dl) * 4096 + s0 + (gs >> 1) * 16;
      const int o0 = (gs & 1) ? 4 : 0;    // pi(lc0)*4
      const int o1 = (gs & 1) ? 12 : 8;   // pi(lc1)*4
      int2 lo; lo.x = u.i4.x; lo.y = u.i4.y;
      int2 hi; hi.x = u.i4.z; hi.y = u.i4.w;
      *(int2*)(vrow + o0) = lo;
      *(int2*)(vrow + o1) = hi;
    }
  }
}

// ---------------------------------------------------------------- kernel: attn
// Block = 4 waves: wave wv -> q-tile (wv&1), key-half (wv>>1); 32 q per wave.
// Per 32-key block: QK = 2x mfma_32x32x16 (A=K m=key, B=Q n=q; chained over
// d halves) -> 16 exp2 in C regs -> pkhu pack -> PV = 2x mfma_32x32x16
// (A=Vp contiguous b128, B=packed P registers). No LDS in the loop.
__global__ __launch_bounds__(256) void k_attn(
    const short* __restrict__ Qr, const short* __restrict__ Kq,
    const short* __restrict__ Vp, short* __restrict__ O) {
  const int tid = threadIdx.x;
  const int L = tid & 63, wv = tid >> 6;
  const int l31 = L & 31, lh = L >> 5;
  const int bh = blockIdx.y;
  const int b = bh >> 3, hd = bh & 7;
  const int qt = wv & 1, half = wv >> 1;
  const int qb = blockIdx.x * 64 + qt * 32;

  const short* Qb = Qr + (size_t)bh * 4096 * 32;
  const short* Kb = Kq + (size_t)bh * 4096 * 32 + half * (2048 * 32);
  const short* Vb = Vp + (size_t)bh * 32 * 4096 + half * 2048;

  __shared__ float cmb[2][32 * 32];   // xor-swizzled combine buffer per q-tile
  __shared__ float l_up[2][32];

  // Q B-frags: lane n=q=l31, k=d=8*lh+j (and +16 for the second d-half)
  short8 qf0 = *(const short8*)(Qb + (qb + l31) * 32 + 8 * lh);
  short8 qf1 = *(const short8*)(Qb + (qb + l31) * 32 + 16 + 8 * lh);

  f16v acc = {0,0,0,0,0,0,0,0,0,0,0,0,0,0,0,0};
  const f16v z16 = {0,0,0,0,0,0,0,0,0,0,0,0,0,0,0,0};
  float lsum = 0.f;

  const short* kp = Kb + l31 * 32 + 8 * lh;            // row=key, col=d
  const short* vpp = Vb + (size_t)l31 * 4096 + 8 * lh; // row=d, col=pos

#pragma unroll 2
  for (int kb = 0; kb < 2048; kb += 32) {
    short8 kf0 = *(const short8*)(kp + kb * 32);
    short8 kf1 = *(const short8*)(kp + kb * 32 + 16);
    short8 vf0 = *(const short8*)(vpp + kb);
    short8 vf1 = *(const short8*)(vpp + kb + 16);
    f16v sc = __builtin_amdgcn_mfma_f32_32x32x16_bf16(kf0, qf0, z16, 0, 0, 0);
    sc = __builtin_amdgcn_mfma_f32_32x32x16_bf16(kf1, qf1, sc, 0, 0, 0);
    float p0  = __builtin_amdgcn_exp2f(sc[0]);
    float p1  = __builtin_amdgcn_exp2f(sc[1]);
    float p2  = __builtin_amdgcn_exp2f(sc[2]);
    float p3  = __builtin_amdgcn_exp2f(sc[3]);
    float p4  = __builtin_amdgcn_exp2f(sc[4]);
    float p5  = __builtin_amdgcn_exp2f(sc[5]);
    float p6  = __builtin_amdgcn_exp2f(sc[6]);
    float p7  = __builtin_amdgcn_exp2f(sc[7]);
    float p8  = __builtin_amdgcn_exp2f(sc[8]);
    float p9  = __builtin_amdgcn_exp2f(sc[9]);
    float p10 = __builtin_amdgcn_exp2f(sc[10]);
    float p11 = __builtin_amdgcn_exp2f(sc[11]);
    float p12 = __builtin_amdgcn_exp2f(sc[12]);
    float p13 = __builtin_amdgcn_exp2f(sc[13]);
    float p14 = __builtin_amdgcn_exp2f(sc[14]);
    float p15 = __builtin_amdgcn_exp2f(sc[15]);
    lsum += (((p0 + p1) + (p2 + p3)) + ((p4 + p5) + (p6 + p7))) +
            (((p8 + p9) + (p10 + p11)) + ((p12 + p13) + (p14 + p15)));
    short8 pb0 = mk8(pkhu(p0, p1), pkhu(p2, p3), pkhu(p4, p5), pkhu(p6, p7));
    short8 pb1 = mk8(pkhu(p8, p9), pkhu(p10, p11), pkhu(p12, p13), pkhu(p14, p15));
    acc = __builtin_amdgcn_mfma_f32_32x32x16_bf16(vf0, pb0, acc, 0, 0, 0);
    acc = __builtin_amdgcn_mfma_f32_32x32x16_bf16(vf1, pb1, acc, 0, 0, 0);
  }

  // full l for q=l31 over this key-half (other lane-half has the other keys)
  const float lf = lsum + __shfl_xor(lsum, 32);

  if (half == 1) {
    float* cw = cmb[qt];
#pragma unroll
    for (int r = 0; r < 16; ++r) {
      const int d = (r & 3) + 8 * (r >> 2) + 4 * lh;
      cw[l31 * 32 + (d ^ l31)] = acc[r];
    }
    if (lh == 0) l_up[qt][l31] = lf;
  }
  __syncthreads();
  if (half == 0) {
    const float* cu = cmb[qt];
    const float rl = 1.0f / (lf + l_up[qt][l31]);
    short* op = O + (size_t)(b * 4096 + qb + l31) * 256 + hd * 32;
#pragma unroll
    for (int g = 0; g < 4; ++g) {
      const int d0 = 4 * lh + 8 * g;
      const float o0 = (acc[4 * g + 0] + cu[l31 * 32 + ((d0 + 0) ^ l31)]) * rl;
      const float o1 = (acc[4 * g + 1] + cu[l31 * 32 + ((d0 + 1) ^ l31)]) * rl;
      const float o2 = (acc[4 * g + 2] + cu[l31 * 32 + ((d0 + 2) ^ l31)]) * rl;
      const float o3 = (acc[4 * g + 3] + cu[l31 * 32 + ((d0 + 3) ^ l31)]) * rl;
      int2 st; st.x = pkrne(o0, o1); st.y = pkrne(o2, o3);
      *(int2*)(op + d0) = st;
    }
  }
}

// ---------------------------------------------------------------- kernel: proj
__global__ __launch_bounds__(256) void k_proj(
    const short* __restrict__ O, const short* __restrict__ wpb,
    const float* __restrict__ bias, float* __restrict__ out) {
  const int tid = threadIdx.x;
  const int L = tid & 63, wv = tid >> 6;
  const int ln15 = L & 15, quad = L >> 4;
  const int m0 = blockIdx.x * 64 + wv * 16;
  const int n0 = blockIdx.y << 6;
  const int b = m0 >> 12, s0 = m0 & 4095;

  f4 acc[4] = {{0,0,0,0},{0,0,0,0},{0,0,0,0},{0,0,0,0}};
  const short* Ob = O + (size_t)(m0 + ln15) * 256 + quad * 8;
  const short* wb = wpb + (n0 + ln15) * 256 + quad * 8;

#pragma unroll
  for (int cb = 0; cb < 256; cb += 32) {
    short8 af = *(const short8*)(Ob + cb);
#pragma unroll
    for (int sub = 0; sub < 4; ++sub) {
      short8 bfr = *(const short8*)(wb + sub * (16 * 256) + cb);
      acc[sub] = __builtin_amdgcn_mfma_f32_16x16x32_bf16(af, bfr, acc[sub], 0, 0, 0);
    }
  }
#pragma unroll
  for (int sub = 0; sub < 4; ++sub) {
    const int c = n0 + sub * 16 + ln15;
    const float bv = bias[c];
    f4 v;
#pragma unroll
    for (int r = 0; r < 4; ++r) v[r] = acc[sub][r] + bv;
    *(f4*)(out + (size_t)b * (256 * 4096) + (size_t)c * 4096 + s0 + quad * 4) = v;
  }
}

// ---------------------------------------------------------------- launcher
extern "C" void kernel_launch(void* const* d_in, const int* in_sizes, int n_in,
                              void* d_out, int out_size, void* d_ws, size_t ws_size,
                              hipStream_t stream) {
  const float* x      = (const float*)d_in[0];
  const float* w_qkv  = (const float*)d_in[1];
  const float* b_qkv  = (const float*)d_in[2];
  const float* w_proj = (const float*)d_in[3];
  const float* b_proj = (const float*)d_in[4];
  float* out = (float*)d_out;

  const size_t SEG = (size_t)4 * 8 * 4096 * 32;  // 4.19M bf16 elems = 8 MiB
  short* Qr  = (short*)d_ws;
  short* Kq  = Qr + SEG;
  short* Vp  = Kq + SEG;
  short* OX  = Vp + SEG;          // xT (b,s,c) until qkv done, then O (b,s,c)
  short* wqb = OX + SEG;
  short* wpb = wqb + 768 * 256;

  k_prep_w<<<256, 256, 0, stream>>>(w_qkv, w_proj, wqb, wpb);
  k_prep_x<<<dim3(64, 4, 4), 256, 0, stream>>>(x, OX);
  k_qkv <<<dim3(256, 12), 256, 0, stream>>>(OX, wqb, b_qkv, Qr, Kq, Vp);
  k_attn<<<dim3(64, 32),  256, 0, stream>>>(Qr, Kq, Vp, OX);
  k_proj<<<dim3(256, 4),  256, 0, stream>>>(OX, wpb, b_proj, out);
}